// Round 6
// baseline (372.249 us; speedup 1.0000x reference)
//
#include <hip/hip_runtime.h>
#include <math.h>

// Problem constants
#define B_    32
#define C3_   1024
#define C4_   2048
#define C_    3072
#define P_    784      // 28*28
#define Q_    196      // 14*14
#define L_    9
#define NG_   25088    // B_*P_
#define A_    312
#define NC_   200

// d_out layout (floats): attr(32x312), class(32x200), maps(32x9x784), af(32x3072x9)
#define ATTR_OFF  0
#define CLASS_OFF 9984
#define MAPS_OFF  16384
#define AF_OFF    242176

// workspace layout (floats)
#define ASQ_OFF   0
#define MF_OFF    16
#define LOGITS_OFF 98320                          // 9 x NG_ = 225792
#define Y_OFF     (LOGITS_OFF + 9 * NG_)          // 324112 ; 32 x 9 x 196
#define MP_OFF    (Y_OFF + 32 * 9 * Q_)           // 380560 ; 32 x 9 x 196
#define PAF_OFF   (MP_OFF + 32 * 9 * Q_)          // 437008 ; 4 x 32 x 1024 x 9
// end: 1616656 floats = 6.5 MB

typedef __attribute__((ext_vector_type(8))) short bf16x8;
typedef __attribute__((ext_vector_type(4))) float f32x4;

__device__ __forceinline__ short f2bf(float f) {
    union { float f; unsigned u; } v; v.f = f;
    unsigned r = v.u + 0x7FFFu + ((v.u >> 16) & 1u);   // RNE
    return (short)(r >> 16);
}

// ====================== zK: zero Y+logits accumulators; block 0 computes a_sq
__global__ __launch_bounds__(256) void zK(const float* __restrict__ conv_w,
                                          float* __restrict__ Y,
                                          float* __restrict__ logits,
                                          float* __restrict__ asq) {
    if (blockIdx.x == 0) {
        __shared__ float red[256];
        int t = threadIdx.x;
        for (int l = 0; l < L_; ++l) {
            float s = 0.f;
            for (int c = t; c < C_; c += 256) s += conv_w[l * C_ + c];
            red[t] = s; __syncthreads();
            for (int o = 128; o > 0; o >>= 1) {
                if (t < o) red[t] += red[t + o];
                __syncthreads();
            }
            if (t == 0) asq[l] = red[0];
            __syncthreads();
        }
        return;
    }
    int i = (blockIdx.x - 1) * 256 + threadIdx.x;
    if (i < 32 * 9 * Q_) Y[i] = 0.f;
    else if (i < 32 * 9 * Q_ + 9 * NG_) logits[i - 32 * 9 * Q_] = 0.f;
}

// ============================================================= K_A (v5)
// Rounds 0-4 post-mortem: four load engines, all ~1.5-1.6 TB/s. Little's law
// back-solve: effective ~2 outstanding loads/wave at ~3000cy loaded latency,
// and occupancy never exceeded ~20 waves/CU. Fix BOTH terms:
//   - 32 waves/CU: no LDS, VGPR ~40 (<64), __launch_bounds__(256,8),
//     2368 blocks (1px/thread).
//   - guaranteed 8-deep loads: 8 independent channel loads pinned live by an
//     empty asm (compiler must issue all 8 before the first FMA consumer).
// In-flight/CU ~ 32 waves x ~2KB = 64KB >> 22KB needed for peak BW.
// blocks [0,1568): l3, slab=bid/98 (block-uniform -> SGPR weights),
//                  g = (bid%98)*256 + t.
// blocks [1568,2368): l4, grp=idx/25, tid2=(idx%25)*256+t < 6272.
// Epilogue: device-scope atomics into logits (x2) / Y (round-4 scheme).
__global__ __launch_bounds__(256, 8) void kA(
        const float* __restrict__ l3, const float* __restrict__ l4,
        const float* __restrict__ conv_w,
        float* __restrict__ logits, float* __restrict__ Y) {
    int bid = blockIdx.x;
    int t = threadIdx.x;

    bool isl3 = (bid < 1568);
    const float* base;
    const float* wbase;
    int pitch;
    int g = 0, b4 = 0, q4 = 0;
    if (isl3) {
        int slab = bid / 98;                  // block-uniform
        g = (bid % 98) * 256 + t;             // exact fit: 98*256 = 25088
        int b = g / 784, px = g % 784;
        base = l3 + ((size_t)b * C3_ + slab * 64) * P_ + px;
        pitch = P_;
        wbase = conv_w + C4_ + slab * 64;
    } else {
        int idx = bid - 1568;
        int grp = idx / 25;                   // block-uniform
        int tid2 = (idx % 25) * 256 + t;
        if (tid2 >= 6272) return;             // wave-uniform exit (tail=128)
        b4 = tid2 / 196; q4 = tid2 % 196;
        base = l4 + ((size_t)b4 * C4_ + grp * 64) * Q_ + q4;
        pitch = Q_;
        wbase = conv_w + grp * 64;
    }

    float acc[9];
#pragma unroll
    for (int l = 0; l < 9; ++l) acc[l] = 0.f;

#pragma unroll
    for (int cb = 0; cb < 8; ++cb) {
        float x0 = base[(size_t)(cb * 8 + 0) * pitch];
        float x1 = base[(size_t)(cb * 8 + 1) * pitch];
        float x2 = base[(size_t)(cb * 8 + 2) * pitch];
        float x3 = base[(size_t)(cb * 8 + 3) * pitch];
        float x4 = base[(size_t)(cb * 8 + 4) * pitch];
        float x5 = base[(size_t)(cb * 8 + 5) * pitch];
        float x6 = base[(size_t)(cb * 8 + 6) * pitch];
        float x7 = base[(size_t)(cb * 8 + 7) * pitch];
        // pin: all 8 loads issued before any FMA consumes one
        asm volatile("" : "+v"(x0), "+v"(x1), "+v"(x2), "+v"(x3),
                          "+v"(x4), "+v"(x5), "+v"(x6), "+v"(x7));
#pragma unroll
        for (int l = 0; l < 9; ++l) {
            float a = acc[l];
            a = fmaf(wbase[l * C_ + cb * 8 + 0], x0, a);
            a = fmaf(wbase[l * C_ + cb * 8 + 1], x1, a);
            a = fmaf(wbase[l * C_ + cb * 8 + 2], x2, a);
            a = fmaf(wbase[l * C_ + cb * 8 + 3], x3, a);
            a = fmaf(wbase[l * C_ + cb * 8 + 4], x4, a);
            a = fmaf(wbase[l * C_ + cb * 8 + 5], x5, a);
            a = fmaf(wbase[l * C_ + cb * 8 + 6], x6, a);
            a = fmaf(wbase[l * C_ + cb * 8 + 7], x7, a);
            acc[l] = a;
        }
    }

    if (isl3) {
#pragma unroll
        for (int l = 0; l < 9; ++l)
            atomicAdd(&logits[(size_t)l * NG_ + g], 2.f * acc[l]);
    } else {
#pragma unroll
        for (int l = 0; l < 9; ++l)
            atomicAdd(&Y[((size_t)b4 * 9 + l) * Q_ + q4], acc[l]);
    }
}

// ====== K_C: maps = softmax_l( logits_accum + 2*upsample(Y) - asq )  (fused)
__global__ __launch_bounds__(256) void kC(const float* __restrict__ logits,
                                          const float* __restrict__ Y,
                                          const float* __restrict__ asq,
                                          float* __restrict__ out_maps) {
    int g = blockIdx.x * 256 + threadIdx.x;   // 98 blocks, exact fit
    int b = g / P_, p = g % P_;
    int yy = p / 28, xx = p % 28;
    float sy = 0.5f * yy - 0.25f, sx = 0.5f * xx - 0.25f;
    float fyf = floorf(sy), fxf = floorf(sx);
    float fy = sy - fyf, fx = sx - fxf;
    int ya = max(0, (int)fyf), yb = min(13, (int)fyf + 1);
    int xa = max(0, (int)fxf), xb = min(13, (int)fxf + 1);
    float w00 = (1.f - fy) * (1.f - fx), w01 = (1.f - fy) * fx;
    float w10 = fy * (1.f - fx),         w11 = fy * fx;
    float v[9];
#pragma unroll
    for (int l = 0; l < 9; ++l) {
        const float* Yl = Y + ((size_t)b * 9 + l) * Q_;
        float ab4 = w00 * Yl[ya * 14 + xa] + w01 * Yl[ya * 14 + xb]
                  + w10 * Yl[yb * 14 + xa] + w11 * Yl[yb * 14 + xb];
        v[l] = logits[(size_t)l * NG_ + g] + 2.f * ab4 - asq[l];
    }
    float m = v[0];
#pragma unroll
    for (int l = 1; l < 9; ++l) m = fmaxf(m, v[l]);
    float sum = 0.f;
#pragma unroll
    for (int l = 0; l < 9; ++l) { v[l] = expf(v[l] - m); sum += v[l]; }
    float inv = 1.f / sum;
#pragma unroll
    for (int l = 0; l < 9; ++l)
        out_maps[(size_t)b * (L_ * P_) + l * P_ + p] = v[l] * inv;
}

// ============== K_D: adjoint bilinear downsample of maps -> Mp[b,l,q]
__device__ __forceinline__ int adj_taps(int q, int* ys, float* wy) {
    if (q == 0)  { ys[0] = 0;  wy[0] = 1.00f; ys[1] = 1;  wy[1] = 0.75f;
                   ys[2] = 2;  wy[2] = 0.25f; return 3; }
    if (q == 13) { ys[0] = 25; wy[0] = 0.25f; ys[1] = 26; wy[1] = 0.75f;
                   ys[2] = 27; wy[2] = 1.00f; return 3; }
    ys[0] = 2 * q - 1; wy[0] = 0.25f;
    ys[1] = 2 * q;     wy[1] = 0.75f;
    ys[2] = 2 * q + 1; wy[2] = 0.75f;
    ys[3] = 2 * q + 2; wy[3] = 0.25f;
    return 4;
}

__global__ __launch_bounds__(256) void kD(const float* __restrict__ maps,
                                          float* __restrict__ Mp) {
    int tid = blockIdx.x * 256 + threadIdx.x;
    if (tid >= 32 * 9 * Q_) return;
    int b = tid / (9 * Q_);
    int r = tid % (9 * Q_);
    int l = r / Q_, q = r % Q_;
    int qy = q / 14, qx = q % 14;
    int ys[4], xs[4]; float wy[4], wx[4];
    int ny = adj_taps(qy, ys, wy);
    int nx = adj_taps(qx, xs, wx);
    const float* mrow = maps + (size_t)b * (L_ * P_) + l * P_;
    float s = 0.f;
    for (int i = 0; i < ny; ++i) {
        float rs = 0.f;
        for (int j = 0; j < nx; ++j)
            rs = fmaf(wx[j], mrow[ys[i] * 28 + xs[j]], rs);
        s = fmaf(wy[i], rs, s);
    }
    Mp[(size_t)b * (9 * Q_) + r] = s;
}

// ===================== K_E: all_features via LDS-staged MFMA bf16 (v5b)
// Round-3 shape (3072 single-chunk blocks, 37KB LDS -> 4 blk/CU, 16 waves)
// + deep staging: ALL 17 float4 loads issued in a straight-line block, then
// __builtin_amdgcn_sched_barrier(0) (no instruction may cross), then the
// convert+LDS-write block. Forces depth-17/wave issue instead of ~2.
// (Round-5 vector "+v" asm pin rejected by hipcc: tied indirect reg inputs.)
// blocks [0,1024): l4 (b, 32 grps of 64) K=196 vs Mp -> writes out_af FINAL
// blocks [1024,3072): l3 (b, 16 grps of 64, 4 K-chunks of 196) -> paf
#define SA 232     // LDS row stride (bf16 elems)
__global__ __launch_bounds__(256, 4) void kE(
        const float* __restrict__ l3, const float* __restrict__ l4,
        const float* __restrict__ maps, const float* __restrict__ Mp,
        float* __restrict__ out_af, float* __restrict__ paf) {
    __shared__ short As[64 * SA];   // 29696 B
    __shared__ short Bs[16 * SA];   //  7424 B
    int bid = blockIdx.x;
    int t = threadIdx.x;
    int wave = t >> 6, lane = t & 63;
    int row16 = lane & 15, quad = lane >> 4;

    const float* xsrc; size_t xstride;
    const float* bsrc; size_t bstride;
    int b, c0, h;
    bool isl4 = (bid < 1024);
    if (isl4) {
        b = bid >> 5;
        c0 = (bid & 31) * 64;
        h = 0;
        xsrc = l4 + ((size_t)b * C4_ + c0) * Q_;
        xstride = Q_;
        bsrc = Mp + (size_t)b * (9 * Q_);
        bstride = Q_;
    } else {
        int idx = bid - 1024;
        b = idx >> 6;
        c0 = ((idx >> 2) & 15) * 64;
        h = idx & 3;
        xsrc = l3 + ((size_t)b * C3_ + c0) * P_ + h * Q_;
        xstride = P_;
        bsrc = maps + (size_t)b * (L_ * P_) + h * Q_;
        bstride = P_;
    }

    // ---- issue ALL staging loads (depth 17), then convert+write ----
    float4 va[13];
    va[12] = make_float4(0.f, 0.f, 0.f, 0.f);
#pragma unroll
    for (int it = 0; it < 12; ++it) {             // 12 x 256 = 3072 (exact)
        int i = t + it * 256;
        int r = i / 49, j = (i % 49) * 4;
        va[it] = *(const float4*)(xsrc + (size_t)r * xstride + j);
    }
    if (t < 64) {                                 // remaining 64 of 3136
        int i = t + 3072;
        int r = i / 49, j = (i % 49) * 4;
        va[12] = *(const float4*)(xsrc + (size_t)r * xstride + j);
    }
    float4 vb[4];
#pragma unroll
    for (int it = 0; it < 4; ++it) {
        int i = t + it * 256;
        vb[it] = make_float4(0.f, 0.f, 0.f, 0.f);
        if (i < 928) {
            int r = i / 58, j = (i % 58) * 4;
            if (r < 9 && j < 196)
                vb[it] = *(const float4*)(bsrc + (size_t)r * bstride + j);
        }
    }
    // scheduling fence: every load above is issued before anything below
    __builtin_amdgcn_sched_barrier(0);

#pragma unroll
    for (int it = 0; it < 12; ++it) {
        int i = t + it * 256;
        int r = i / 49, j = (i % 49) * 4;
        ushort4 o;
        o.x = (unsigned short)f2bf(va[it].x); o.y = (unsigned short)f2bf(va[it].y);
        o.z = (unsigned short)f2bf(va[it].z); o.w = (unsigned short)f2bf(va[it].w);
        *(ushort4*)(As + r * SA + j) = o;
    }
    if (t < 64) {
        int i = t + 3072;
        int r = i / 49, j = (i % 49) * 4;
        ushort4 o;
        o.x = (unsigned short)f2bf(va[12].x); o.y = (unsigned short)f2bf(va[12].y);
        o.z = (unsigned short)f2bf(va[12].z); o.w = (unsigned short)f2bf(va[12].w);
        *(ushort4*)(As + r * SA + j) = o;
    }
    // A-tile K-pad (cols 196..231) zero
    for (int i = t; i < 64 * 9; i += 256) {
        int r = i / 9, j = 196 + (i % 9) * 4;
        *(ushort4*)(As + r * SA + j) = make_ushort4(0, 0, 0, 0);
    }
#pragma unroll
    for (int it = 0; it < 4; ++it) {
        int i = t + it * 256;
        if (i < 928) {
            int r = i / 58, j = (i % 58) * 4;
            ushort4 o;
            o.x = (unsigned short)f2bf(vb[it].x); o.y = (unsigned short)f2bf(vb[it].y);
            o.z = (unsigned short)f2bf(vb[it].z); o.w = (unsigned short)f2bf(vb[it].w);
            *(ushort4*)(Bs + r * SA + j) = o;
        }
    }
    __syncthreads();

    const short* arow = As + (wave * 16 + row16) * SA;
    const short* brow = Bs + row16 * SA;
    f32x4 acc = {0.f, 0.f, 0.f, 0.f};
#pragma unroll
    for (int k0 = 0; k0 < 224; k0 += 32) {
        bf16x8 a = *(const bf16x8*)(arow + k0 + quad * 8);
        bf16x8 bv = *(const bf16x8*)(brow + k0 + quad * 8);
        acc = __builtin_amdgcn_mfma_f32_16x16x32_bf16(a, bv, acc, 0, 0, 0);
    }
    int l = row16;
    if (l < 9) {
        int c = c0 + wave * 16 + quad * 4;
        if (isl4) {
            size_t base = ((size_t)b * C_ + c) * 9 + l;
#pragma unroll
            for (int r = 0; r < 4; ++r)
                out_af[base + (size_t)r * 9] = acc[r] * (1.f / 784.f);
        } else {
            size_t base = ((size_t)(h * B_ + b) * C3_ + c) * 9 + l;
#pragma unroll
            for (int r = 0; r < 4; ++r)
                paf[base + (size_t)r * 9] = acc[r];
        }
    }
}

// ============ K_MF: combine l3 partials -> af, and mean_features for all c
__global__ __launch_bounds__(256) void kMF(const float* __restrict__ paf,
                                           const float* __restrict__ mod,
                                           float* __restrict__ out_af,
                                           float* __restrict__ mf) {
    int i = blockIdx.x * 256 + threadIdx.x;   // b*C + c
    if (i >= B_ * C_) return;
    int b = i / C_, c = i % C_;
    float af[9];
    if (c < C4_) {
#pragma unroll
        for (int l = 0; l < 9; ++l) af[l] = out_af[(size_t)i * 9 + l];
    } else {
        int c3 = c - C4_;
#pragma unroll
        for (int l = 0; l < 9; ++l) {
            float s = 0.f;
#pragma unroll
            for (int hh = 0; hh < 4; ++hh)
                s += paf[((size_t)(hh * B_ + b) * C3_ + c3) * 9 + l];
            af[l] = s * (1.f / 784.f);
            out_af[(size_t)i * 9 + l] = af[l];
        }
    }
    const float* m = mod + (size_t)c * 9;
    float s = 0.f;
#pragma unroll
    for (int l = 0; l < 8; ++l) s = fmaf(af[l], m[l], s);
    mf[i] = s * 0.125f;
}

// -------------------------------------------------- K_F: attr = mf @ attr_w.T
__global__ __launch_bounds__(256) void kF(
        const float* __restrict__ mf, const float* __restrict__ attr_w,
        const float* __restrict__ attr_b, float* __restrict__ out_attr) {
    int idx = blockIdx.x * 4 + (threadIdx.x >> 6);   // idx = b*312 + a
    int lane = threadIdx.x & 63;
    int b = idx / A_, a = idx % A_;
    const float4* wr = (const float4*)(attr_w + (size_t)a * C_);
    const float4* mr = (const float4*)(mf + (size_t)b * C_);
    float acc = 0.f;
    for (int j = lane; j < C_ / 4; j += 64) {
        float4 w = wr[j], m = mr[j];
        acc += w.x * m.x + w.y * m.y + w.z * m.z + w.w * m.w;
    }
    acc += __shfl_xor(acc, 1);  acc += __shfl_xor(acc, 2);
    acc += __shfl_xor(acc, 4);  acc += __shfl_xor(acc, 8);
    acc += __shfl_xor(acc, 16); acc += __shfl_xor(acc, 32);
    if (lane == 0) out_attr[idx] = acc + attr_b[a];
}

// ---------------------------------------------- K_G: class = attr @ class_w.T
__global__ __launch_bounds__(256) void kG(
        const float* __restrict__ attr, const float* __restrict__ class_w,
        float* __restrict__ out_class) {
    int idx = blockIdx.x * 4 + (threadIdx.x >> 6);   // idx = b*200 + n
    int lane = threadIdx.x & 63;
    int b = idx / NC_, n = idx % NC_;
    float acc = 0.f;
    for (int a = lane; a < A_; a += 64)
        acc += attr[b * A_ + a] * class_w[n * A_ + a];
    acc += __shfl_xor(acc, 1);  acc += __shfl_xor(acc, 2);
    acc += __shfl_xor(acc, 4);  acc += __shfl_xor(acc, 8);
    acc += __shfl_xor(acc, 16); acc += __shfl_xor(acc, 32);
    if (lane == 0) out_class[idx] = acc;
}

extern "C" void kernel_launch(void* const* d_in, const int* in_sizes, int n_in,
                              void* d_out, int out_size, void* d_ws, size_t ws_size,
                              hipStream_t stream) {
    (void)in_sizes; (void)n_in; (void)out_size; (void)ws_size;
    const float* l3         = (const float*)d_in[0];
    const float* l4         = (const float*)d_in[1];
    const float* conv_w     = (const float*)d_in[2];
    const float* modulation = (const float*)d_in[3];
    const float* attr_w     = (const float*)d_in[4];
    const float* attr_b     = (const float*)d_in[5];
    const float* class_w    = (const float*)d_in[6];
    float* out = (float*)d_out;
    float* ws  = (float*)d_ws;
    float* asq    = ws + ASQ_OFF;
    float* mf     = ws + MF_OFF;
    float* logits = ws + LOGITS_OFF;
    float* Y      = ws + Y_OFF;
    float* Mp     = ws + MP_OFF;
    float* paf    = ws + PAF_OFF;

    zK<<<1104, 256, 0, stream>>>(conv_w, Y, logits, asq);
    kA<<<2368, 256, 0, stream>>>(l3, l4, conv_w, logits, Y);
    kC<<<98, 256, 0, stream>>>(logits, Y, asq, out + MAPS_OFF);
    kD<<<221, 256, 0, stream>>>(out + MAPS_OFF, Mp);
    kE<<<3072, 256, 0, stream>>>(l3, l4, out + MAPS_OFF, Mp, out + AF_OFF, paf);
    kMF<<<384, 256, 0, stream>>>(paf, modulation, out + AF_OFF, mf);
    kF<<<(B_ * A_) / 4, 256, 0, stream>>>(mf, attr_w, attr_b, out + ATTR_OFF);
    kG<<<(B_ * NC_) / 4, 256, 0, stream>>>(out + ATTR_OFF, class_w,
                                           out + CLASS_OFF);
}

// Round 7
// 323.402 us; speedup vs baseline: 1.1510x; 1.1510x over previous
//
#include <hip/hip_runtime.h>
#include <math.h>

// Problem constants
#define B_    32
#define C3_   1024
#define C4_   2048
#define C_    3072
#define P_    784      // 28*28
#define Q_    196      // 14*14
#define L_    9
#define NG_   25088    // B_*P_
#define A_    312
#define NC_   200

// d_out layout (floats): attr(32x312), class(32x200), maps(32x9x784), af(32x3072x9)
#define ATTR_OFF  0
#define CLASS_OFF 9984
#define MAPS_OFF  16384
#define AF_OFF    242176

// workspace layout (floats)
#define ASQ_OFF   0
#define MF_OFF    16
#define LOGITS_OFF 98320                          // 9 x NG_ = 225792
#define Y_OFF     (LOGITS_OFF + 9 * NG_)          // 324112 ; 32 x 9 x 196
#define MP_OFF    (Y_OFF + 32 * 9 * Q_)           // 380560 ; 32 x 9 x 196
// end: ~437k floats = 1.7 MB

typedef __attribute__((ext_vector_type(8))) short bf16x8;
typedef __attribute__((ext_vector_type(4))) float f32x4;

__device__ __forceinline__ short f2bf(float f) {
    union { float f; unsigned u; } v; v.f = f;
    unsigned r = v.u + 0x7FFFu + ((v.u >> 16) & 1u);   // RNE
    return (short)(r >> 16);
}

// async global->LDS, 16B per lane, LDS dest = uniform base + lane*16,
// global src = PER-LANE address (m104/m108).
#define GLDS16(gp, lp) __builtin_amdgcn_global_load_lds(                    \
        (const __attribute__((address_space(1))) unsigned int*)(gp),        \
        (__attribute__((address_space(3))) unsigned int*)(lp), 16, 0, 0)

// ====================== zK: zero Y+logits accumulators; block 0 computes a_sq
__global__ __launch_bounds__(256) void zK(const float* __restrict__ conv_w,
                                          float* __restrict__ Y,
                                          float* __restrict__ logits,
                                          float* __restrict__ asq) {
    if (blockIdx.x == 0) {
        __shared__ float red[256];
        int t = threadIdx.x;
        for (int l = 0; l < L_; ++l) {
            float s = 0.f;
            for (int c = t; c < C_; c += 256) s += conv_w[l * C_ + c];
            red[t] = s; __syncthreads();
            for (int o = 128; o > 0; o >>= 1) {
                if (t < o) red[t] += red[t + o];
                __syncthreads();
            }
            if (t == 0) asq[l] = red[0];
            __syncthreads();
        }
        return;
    }
    int i = (blockIdx.x - 1) * 256 + threadIdx.x;
    if (i < 32 * 9 * Q_) Y[i] = 0.f;
    else if (i < 32 * 9 * Q_ + 9 * NG_) logits[i - 32 * 9 * Q_] = 0.f;
}

// ============================================================= K_A (round-4)
// Best measured engine (65us, 2.5 TB/s total-traffic): chunked GLDS pipeline,
// 2x16KB LDS dbuf (5 blk/CU), 64ch = 4 chunks of 16, counted vmcnt(4),
// device-scope atomic epilogue into logits (x2) / Y.
//   blocks [0,1568): l3.  slab = bid/98, g-tile = bid%98.
//   blocks [1568,2592): l4. b = idx>>5, grp = idx&31.
__global__ __launch_bounds__(256, 5) void kA(
        const float* __restrict__ l3, const float* __restrict__ l4,
        const float* __restrict__ conv_w,
        float* __restrict__ logits, float* __restrict__ Y) {
    __shared__ float X[2][16 * 256];   // 32768 B -> 5 blocks/CU
    int bid = blockIdx.x;
    int t = threadIdx.x;
    int wave = t >> 6, lane = t & 63;

    bool isl3 = (bid < 1568);
    int slab = 0, g0 = 0, b = 0, grp = 0, cbase_w;
    const float* gbase;     // per-lane base address for channel-row 0
    size_t rowpitch;
    if (isl3) {
        slab = bid / 98;                 // block-uniform
        g0 = (bid % 98) * 256;
        int gidx = g0 + lane * 4;        // 4 floats (16B) per lane
        int bb = gidx / 784, px = gidx % 784;   // 4 | 784 -> no group split
        gbase = l3 + ((size_t)bb * C3_ + slab * 64) * P_ + px;
        rowpitch = P_;
        cbase_w = C4_ + slab * 64;
    } else {
        int idx = bid - 1568;
        b = idx >> 5; grp = idx & 31;    // block-uniform
        int q = lane * 4;
        if (q > 192) q = 192;            // lanes 49..63: dup same 16B (1 line)
        gbase = l4 + ((size_t)b * C4_ + grp * 64) * Q_ + q;
        rowpitch = Q_;
        cbase_w = grp * 64;
    }

    // prologue: chunk 0 -> buf 0 (wave w stages in-chunk rows w*4..w*4+3)
#pragma unroll
    for (int r = 0; r < 4; ++r) {
        int row = wave * 4 + r;
        GLDS16(gbase + (size_t)row * rowpitch, &X[0][row * 256]);
    }

    float acc[9];
#pragma unroll
    for (int l = 0; l < 9; ++l) acc[l] = 0.f;

#pragma unroll
    for (int j = 0; j < 4; ++j) {
        const int cur = j & 1;
        if (j < 3) {
#pragma unroll
            for (int r = 0; r < 4; ++r) {
                int row = wave * 4 + r;           // in-chunk row
                int ch = (j + 1) * 16 + row;      // global channel row
                GLDS16(gbase + (size_t)ch * rowpitch, &X[cur ^ 1][row * 256]);
            }
            // counted wait: own chunk-j loads (oldest 4) done; chunk j+1's
            // 4 loads stay in flight across the barrier.
            asm volatile("s_waitcnt vmcnt(4)" ::: "memory");
        } else {
            asm volatile("s_waitcnt vmcnt(0)" ::: "memory");
        }
        __builtin_amdgcn_s_barrier();      // all waves' chunk-j rows in LDS

        if (isl3 || t < 196) {
#pragma unroll
            for (int c = 0; c < 16; ++c) {
                float x = X[cur][c * 256 + t];
#pragma unroll
                for (int l = 0; l < 9; ++l)
                    acc[l] = fmaf(conv_w[(size_t)l * C_ + cbase_w + j * 16 + c],
                                  x, acc[l]);
            }
        }
        __builtin_amdgcn_s_barrier();      // reads done before buf reuse
    }

    if (isl3) {
#pragma unroll
        for (int l = 0; l < 9; ++l)
            atomicAdd(&logits[(size_t)l * NG_ + g0 + t], 2.f * acc[l]);
    } else if (t < 196) {
#pragma unroll
        for (int l = 0; l < 9; ++l)
            atomicAdd(&Y[((size_t)b * 9 + l) * Q_ + t], acc[l]);
    }
}

// ====== K_C: maps = softmax_l( logits_accum + 2*upsample(Y) - asq )  (fused)
__global__ __launch_bounds__(256) void kC(const float* __restrict__ logits,
                                          const float* __restrict__ Y,
                                          const float* __restrict__ asq,
                                          float* __restrict__ out_maps) {
    int g = blockIdx.x * 256 + threadIdx.x;   // 98 blocks, exact fit
    int b = g / P_, p = g % P_;
    int yy = p / 28, xx = p % 28;
    float sy = 0.5f * yy - 0.25f, sx = 0.5f * xx - 0.25f;
    float fyf = floorf(sy), fxf = floorf(sx);
    float fy = sy - fyf, fx = sx - fxf;
    int ya = max(0, (int)fyf), yb = min(13, (int)fyf + 1);
    int xa = max(0, (int)fxf), xb = min(13, (int)fxf + 1);
    float w00 = (1.f - fy) * (1.f - fx), w01 = (1.f - fy) * fx;
    float w10 = fy * (1.f - fx),         w11 = fy * fx;
    float v[9];
#pragma unroll
    for (int l = 0; l < 9; ++l) {
        const float* Yl = Y + ((size_t)b * 9 + l) * Q_;
        float ab4 = w00 * Yl[ya * 14 + xa] + w01 * Yl[ya * 14 + xb]
                  + w10 * Yl[yb * 14 + xa] + w11 * Yl[yb * 14 + xb];
        v[l] = logits[(size_t)l * NG_ + g] + 2.f * ab4 - asq[l];
    }
    float m = v[0];
#pragma unroll
    for (int l = 1; l < 9; ++l) m = fmaxf(m, v[l]);
    float sum = 0.f;
#pragma unroll
    for (int l = 0; l < 9; ++l) { v[l] = expf(v[l] - m); sum += v[l]; }
    float inv = 1.f / sum;
#pragma unroll
    for (int l = 0; l < 9; ++l)
        out_maps[(size_t)b * (L_ * P_) + l * P_ + p] = v[l] * inv;
}

// ============== K_D: adjoint bilinear downsample of maps -> Mp[b,l,q]
__device__ __forceinline__ int adj_taps(int q, int* ys, float* wy) {
    if (q == 0)  { ys[0] = 0;  wy[0] = 1.00f; ys[1] = 1;  wy[1] = 0.75f;
                   ys[2] = 2;  wy[2] = 0.25f; return 3; }
    if (q == 13) { ys[0] = 25; wy[0] = 0.25f; ys[1] = 26; wy[1] = 0.75f;
                   ys[2] = 27; wy[2] = 1.00f; return 3; }
    ys[0] = 2 * q - 1; wy[0] = 0.25f;
    ys[1] = 2 * q;     wy[1] = 0.75f;
    ys[2] = 2 * q + 1; wy[2] = 0.75f;
    ys[3] = 2 * q + 2; wy[3] = 0.25f;
    return 4;
}

__global__ __launch_bounds__(256) void kD(const float* __restrict__ maps,
                                          float* __restrict__ Mp) {
    int tid = blockIdx.x * 256 + threadIdx.x;
    if (tid >= 32 * 9 * Q_) return;
    int b = tid / (9 * Q_);
    int r = tid % (9 * Q_);
    int l = r / Q_, q = r % Q_;
    int qy = q / 14, qx = q % 14;
    int ys[4], xs[4]; float wy[4], wx[4];
    int ny = adj_taps(qy, ys, wy);
    int nx = adj_taps(qx, xs, wx);
    const float* mrow = maps + (size_t)b * (L_ * P_) + l * P_;
    float s = 0.f;
    for (int i = 0; i < ny; ++i) {
        float rs = 0.f;
        for (int j = 0; j < nx; ++j)
            rs = fmaf(wx[j], mrow[ys[i] * 28 + xs[j]], rs);
        s = fmaf(wy[i], rs, s);
    }
    Mp[(size_t)b * (9 * Q_) + r] = s;
}

// ===================== K_E (v7): GLDS-staged MFMA, per-wave private tiles
// Port of kA's proven 2.5 TB/s engine. Each wave owns a PRIVATE LDS region
// (13 KB packed fp32 16ch x 196px) filled by 13 fire-and-forget GLDS16
// (per-lane src, linear dest). Zero barriers: vmcnt is per-wave state and
// regions are private. B fragments (maps/Mp, L2/L3-hot) load to registers
// under the GLDS latency. fp32->bf16 conversion happens on LDS read.
// blocks [0,1024): l4, b=bid>>5, grp 0..31, K=196 (1 chunk) vs Mp.
// blocks [1024,1536): l3, b=idx>>4, grp 0..15, K=784 (4 chunks, acc carried).
// Epilogue: af FINAL (/784) + mf via 16-lane shfl tree -> kMF deleted.
#define WREG 3328   // floats per wave region (13 KB + 768 B pad)
__global__ __launch_bounds__(256, 3) void kE(
        const float* __restrict__ l3, const float* __restrict__ l4,
        const float* __restrict__ maps, const float* __restrict__ Mp,
        const float* __restrict__ mod,
        float* __restrict__ out_af, float* __restrict__ mf) {
    __shared__ float X[4 * WREG];          // 53248 B -> 3 blocks/CU
    int bid = blockIdx.x;
    int t = threadIdx.x;
    int wave = t >> 6, lane = t & 63;
    int row16 = lane & 15, quad = lane >> 4;

    bool isl4 = (bid < 1024);
    int b, c0, nchunk, cglob0, pitch;
    const float* xsrc; const float* bsrc;
    if (isl4) {
        b = bid >> 5; c0 = (bid & 31) * 64; nchunk = 1;
        xsrc = l4 + ((size_t)b * C4_ + c0) * Q_;
        bsrc = Mp + (size_t)b * (9 * Q_);
        pitch = Q_;
        cglob0 = c0;
    } else {
        int idx = bid - 1024;
        b = idx >> 4; c0 = (idx & 15) * 64; nchunk = 4;
        xsrc = l3 + ((size_t)b * C3_ + c0) * P_;
        bsrc = maps + (size_t)b * (L_ * P_);
        pitch = P_;
        cglob0 = C4_ + c0;
    }
    const float* wrow = xsrc + (size_t)(wave * 16) * pitch;  // wave's 16 rows
    float* Xw = X + wave * WREG;

    f32x4 acc = {0.f, 0.f, 0.f, 0.f};
    for (int h = 0; h < nchunk; ++h) {
        int koff = h * 196;
        // ---- issue 13 x 1KB GLDS: packed 16 rows x 196 floats ----
#pragma unroll
        for (int k = 0; k < 13; ++k) {
            int f = k * 256 + lane * 4;        // packed float index
            if (f > 3132) f = 3132;            // clamp pad lanes (k=12,l>=16)
            int r = f / 196, j = f % 196;      // j%4==0, j<=192: no straddle
            GLDS16(wrow + (size_t)r * pitch + koff + j, &Xw[k * 256]);
        }
        // ---- B fragments from global (L2-hot), overlapping GLDS latency ----
        bf16x8 bfr[7];
#pragma unroll
        for (int s = 0; s < 7; ++s) {
            int k0 = s * 32 + quad * 8;
            bf16x8 bv = {0, 0, 0, 0, 0, 0, 0, 0};
            if (row16 < 9) {
                const float* bp = bsrc + (size_t)row16 * pitch + koff + k0;
                if (s < 6) {
                    float4 b0 = *(const float4*)(bp);
                    float4 b1 = *(const float4*)(bp + 4);
                    bv[0] = f2bf(b0.x); bv[1] = f2bf(b0.y);
                    bv[2] = f2bf(b0.z); bv[3] = f2bf(b0.w);
                    bv[4] = f2bf(b1.x); bv[5] = f2bf(b1.y);
                    bv[6] = f2bf(b1.z); bv[7] = f2bf(b1.w);
                } else if (quad == 0) {        // k0=192: cols 192..195 only
                    float4 b0 = *(const float4*)(bp);
                    bv[0] = f2bf(b0.x); bv[1] = f2bf(b0.y);
                    bv[2] = f2bf(b0.z); bv[3] = f2bf(b0.w);
                }
            }
            bfr[s] = bv;
        }
        // own GLDS done (per-wave counter; no barrier needed: region private)
        asm volatile("s_waitcnt vmcnt(0)" ::: "memory");

        // ---- 7 k-steps: LDS fp32 -> bf16 frags -> MFMA ----
#pragma unroll
        for (int s = 0; s < 7; ++s) {
            int k0 = s * 32 + quad * 8;
            bf16x8 av = {0, 0, 0, 0, 0, 0, 0, 0};
            const float* ap = Xw + row16 * 196 + k0;
            if (s < 6) {
                float4 a0 = *(const float4*)(ap);
                float4 a1 = *(const float4*)(ap + 4);
                av[0] = f2bf(a0.x); av[1] = f2bf(a0.y);
                av[2] = f2bf(a0.z); av[3] = f2bf(a0.w);
                av[4] = f2bf(a1.x); av[5] = f2bf(a1.y);
                av[6] = f2bf(a1.z); av[7] = f2bf(a1.w);
            } else if (quad == 0) {            // k0=192: cols 192..195 only
                float4 a0 = *(const float4*)(ap);
                av[0] = f2bf(a0.x); av[1] = f2bf(a0.y);
                av[2] = f2bf(a0.z); av[3] = f2bf(a0.w);
            }
            acc = __builtin_amdgcn_mfma_f32_16x16x32_bf16(av, bfr[s], acc,
                                                          0, 0, 0);
        }
        if (h + 1 < nchunk) {
            // LDS reads retired before next chunk's GLDS overwrites region
            asm volatile("s_waitcnt lgkmcnt(0)" ::: "memory");
            __builtin_amdgcn_sched_barrier(0);
        }
    }

    // ---- epilogue: af (final) + mf (round-4 scheme, verified) ----
    int l = row16;
    int cg = cglob0 + wave * 16 + quad * 4;
    float afv[4];
#pragma unroll
    for (int r = 0; r < 4; ++r) afv[r] = acc[r] * (1.f / 784.f);
    if (l < 9) {
        size_t base = ((size_t)b * C_ + cg) * 9 + l;
#pragma unroll
        for (int r = 0; r < 4; ++r) out_af[base + (size_t)r * 9] = afv[r];
    }
    float term[4];
#pragma unroll
    for (int r = 0; r < 4; ++r)
        term[r] = (l < 8) ? afv[r] * mod[(size_t)(cg + r) * 9 + l] : 0.f;
#pragma unroll
    for (int s = 1; s < 16; s <<= 1)
#pragma unroll
        for (int r = 0; r < 4; ++r) term[r] += __shfl_xor(term[r], s);
    if (row16 == 0) {
#pragma unroll
        for (int r = 0; r < 4; ++r)
            mf[(size_t)b * C_ + cg + r] = term[r] * 0.125f;
    }
}

// -------------------------------------------------- K_F: attr = mf @ attr_w.T
__global__ __launch_bounds__(256) void kF(
        const float* __restrict__ mf, const float* __restrict__ attr_w,
        const float* __restrict__ attr_b, float* __restrict__ out_attr) {
    int idx = blockIdx.x * 4 + (threadIdx.x >> 6);   // idx = b*312 + a
    int lane = threadIdx.x & 63;
    int b = idx / A_, a = idx % A_;
    const float4* wr = (const float4*)(attr_w + (size_t)a * C_);
    const float4* mr = (const float4*)(mf + (size_t)b * C_);
    float acc = 0.f;
    for (int j = lane; j < C_ / 4; j += 64) {
        float4 w = wr[j], m = mr[j];
        acc += w.x * m.x + w.y * m.y + w.z * m.z + w.w * m.w;
    }
    acc += __shfl_xor(acc, 1);  acc += __shfl_xor(acc, 2);
    acc += __shfl_xor(acc, 4);  acc += __shfl_xor(acc, 8);
    acc += __shfl_xor(acc, 16); acc += __shfl_xor(acc, 32);
    if (lane == 0) out_attr[idx] = acc + attr_b[a];
}

// ---------------------------------------------- K_G: class = attr @ class_w.T
__global__ __launch_bounds__(256) void kG(
        const float* __restrict__ attr, const float* __restrict__ class_w,
        float* __restrict__ out_class) {
    int idx = blockIdx.x * 4 + (threadIdx.x >> 6);   // idx = b*200 + n
    int lane = threadIdx.x & 63;
    int b = idx / NC_, n = idx % NC_;
    float acc = 0.f;
    for (int a = lane; a < A_; a += 64)
        acc += attr[b * A_ + a] * class_w[n * A_ + a];
    acc += __shfl_xor(acc, 1);  acc += __shfl_xor(acc, 2);
    acc += __shfl_xor(acc, 4);  acc += __shfl_xor(acc, 8);
    acc += __shfl_xor(acc, 16); acc += __shfl_xor(acc, 32);
    if (lane == 0) out_class[idx] = acc;
}

extern "C" void kernel_launch(void* const* d_in, const int* in_sizes, int n_in,
                              void* d_out, int out_size, void* d_ws, size_t ws_size,
                              hipStream_t stream) {
    (void)in_sizes; (void)n_in; (void)out_size; (void)ws_size;
    const float* l3         = (const float*)d_in[0];
    const float* l4         = (const float*)d_in[1];
    const float* conv_w     = (const float*)d_in[2];
    const float* modulation = (const float*)d_in[3];
    const float* attr_w     = (const float*)d_in[4];
    const float* attr_b     = (const float*)d_in[5];
    const float* class_w    = (const float*)d_in[6];
    float* out = (float*)d_out;
    float* ws  = (float*)d_ws;
    float* asq    = ws + ASQ_OFF;
    float* mf     = ws + MF_OFF;
    float* logits = ws + LOGITS_OFF;
    float* Y      = ws + Y_OFF;
    float* Mp     = ws + MP_OFF;

    zK<<<1104, 256, 0, stream>>>(conv_w, Y, logits, asq);
    kA<<<2592, 256, 0, stream>>>(l3, l4, conv_w, logits, Y);
    kC<<<98, 256, 0, stream>>>(logits, Y, asq, out + MAPS_OFF);
    kD<<<221, 256, 0, stream>>>(out + MAPS_OFF, Mp);
    kE<<<1536, 256, 0, stream>>>(l3, l4, out + MAPS_OFF, Mp, modulation,
                                 out + AF_OFF, mf);
    kF<<<(B_ * A_) / 4, 256, 0, stream>>>(mf, attr_w, attr_b, out + ATTR_OFF);
    kG<<<(B_ * NC_) / 4, 256, 0, stream>>>(out + ATTR_OFF, class_w,
                                           out + CLASS_OFF);
}

// Round 8
// 303.790 us; speedup vs baseline: 1.2253x; 1.0646x over previous
//
#include <hip/hip_runtime.h>
#include <math.h>

// Problem constants
#define B_    32
#define C3_   1024
#define C4_   2048
#define C_    3072
#define P_    784      // 28*28
#define Q_    196      // 14*14
#define L_    9
#define NG_   25088    // B_*P_
#define A_    312
#define NC_   200

// d_out layout (floats): attr(32x312), class(32x200), maps(32x9x784), af(32x3072x9)
#define ATTR_OFF  0
#define CLASS_OFF 9984
#define MAPS_OFF  16384
#define AF_OFF    242176

// workspace layout (floats)
#define ASQ_OFF   0
#define MF_OFF    16
#define LOGITS_OFF 98320                          // 9 x NG_ = 225792
#define Y_OFF     (LOGITS_OFF + 9 * NG_)          // 324112 ; 32 x 9 x 196
#define MP_OFF    (Y_OFF + 32 * 9 * Q_)           // 380560 ; 32 x 9 x 196
// end: ~437k floats = 1.7 MB

typedef __attribute__((ext_vector_type(8))) short bf16x8;
typedef __attribute__((ext_vector_type(4))) float f32x4;

__device__ __forceinline__ short f2bf(float f) {
    union { float f; unsigned u; } v; v.f = f;
    unsigned r = v.u + 0x7FFFu + ((v.u >> 16) & 1u);   // RNE
    return (short)(r >> 16);
}

// async global->LDS, 16B per lane, LDS dest = uniform base + lane*16
#define GLDS16(gp, lp) __builtin_amdgcn_global_load_lds(                    \
        (const __attribute__((address_space(1))) unsigned int*)(gp),        \
        (__attribute__((address_space(3))) unsigned int*)(lp), 16, 0, 0)

// ====================== zK: zero Y+logits accumulators; block 0 computes a_sq
__global__ __launch_bounds__(256) void zK(const float* __restrict__ conv_w,
                                          float* __restrict__ Y,
                                          float* __restrict__ logits,
                                          float* __restrict__ asq) {
    if (blockIdx.x == 0) {
        __shared__ float red[256];
        int t = threadIdx.x;
        for (int l = 0; l < L_; ++l) {
            float s = 0.f;
            for (int c = t; c < C_; c += 256) s += conv_w[l * C_ + c];
            red[t] = s; __syncthreads();
            for (int o = 128; o > 0; o >>= 1) {
                if (t < o) red[t] += red[t + o];
                __syncthreads();
            }
            if (t == 0) asq[l] = red[0];
            __syncthreads();
        }
        return;
    }
    int i = (blockIdx.x - 1) * 256 + threadIdx.x;
    if (i < 32 * 9 * Q_) Y[i] = 0.f;
    else if (i < 32 * 9 * Q_ + 9 * NG_) logits[i - 32 * 9 * Q_] = 0.f;
}

// ============================================================= K_A (round-4)
// Best measured engine (65us): chunked GLDS pipeline, 2x16KB LDS dbuf
// (5 blk/CU), 64ch = 4 chunks of 16, counted vmcnt(4), device-scope atomic
// epilogue into logits (x2) / Y.
//   blocks [0,1568): l3.  slab = bid/98, g-tile = bid%98.
//   blocks [1568,2592): l4. b = idx>>5, grp = idx&31.
__global__ __launch_bounds__(256, 5) void kA(
        const float* __restrict__ l3, const float* __restrict__ l4,
        const float* __restrict__ conv_w,
        float* __restrict__ logits, float* __restrict__ Y) {
    __shared__ float X[2][16 * 256];   // 32768 B -> 5 blocks/CU
    int bid = blockIdx.x;
    int t = threadIdx.x;
    int wave = t >> 6, lane = t & 63;

    bool isl3 = (bid < 1568);
    int slab = 0, g0 = 0, b = 0, grp = 0, cbase_w;
    const float* gbase;     // per-lane base address for channel-row 0
    size_t rowpitch;
    if (isl3) {
        slab = bid / 98;                 // block-uniform
        g0 = (bid % 98) * 256;
        int gidx = g0 + lane * 4;        // 4 floats (16B) per lane
        int bb = gidx / 784, px = gidx % 784;   // 4 | 784 -> no group split
        gbase = l3 + ((size_t)bb * C3_ + slab * 64) * P_ + px;
        rowpitch = P_;
        cbase_w = C4_ + slab * 64;
    } else {
        int idx = bid - 1568;
        b = idx >> 5; grp = idx & 31;    // block-uniform
        int q = lane * 4;
        if (q > 192) q = 192;            // lanes 49..63: dup same 16B (1 line)
        gbase = l4 + ((size_t)b * C4_ + grp * 64) * Q_ + q;
        rowpitch = Q_;
        cbase_w = grp * 64;
    }

    // prologue: chunk 0 -> buf 0 (wave w stages in-chunk rows w*4..w*4+3)
#pragma unroll
    for (int r = 0; r < 4; ++r) {
        int row = wave * 4 + r;
        GLDS16(gbase + (size_t)row * rowpitch, &X[0][row * 256]);
    }

    float acc[9];
#pragma unroll
    for (int l = 0; l < 9; ++l) acc[l] = 0.f;

#pragma unroll
    for (int j = 0; j < 4; ++j) {
        const int cur = j & 1;
        if (j < 3) {
#pragma unroll
            for (int r = 0; r < 4; ++r) {
                int row = wave * 4 + r;           // in-chunk row
                int ch = (j + 1) * 16 + row;      // global channel row
                GLDS16(gbase + (size_t)ch * rowpitch, &X[cur ^ 1][row * 256]);
            }
            // counted wait: own chunk-j loads (oldest 4) done; chunk j+1's
            // 4 loads stay in flight across the barrier.
            asm volatile("s_waitcnt vmcnt(4)" ::: "memory");
        } else {
            asm volatile("s_waitcnt vmcnt(0)" ::: "memory");
        }
        __builtin_amdgcn_s_barrier();      // all waves' chunk-j rows in LDS

        if (isl3 || t < 196) {
#pragma unroll
            for (int c = 0; c < 16; ++c) {
                float x = X[cur][c * 256 + t];
#pragma unroll
                for (int l = 0; l < 9; ++l)
                    acc[l] = fmaf(conv_w[(size_t)l * C_ + cbase_w + j * 16 + c],
                                  x, acc[l]);
            }
        }
        __builtin_amdgcn_s_barrier();      // reads done before buf reuse
    }

    if (isl3) {
#pragma unroll
        for (int l = 0; l < 9; ++l)
            atomicAdd(&logits[(size_t)l * NG_ + g0 + t], 2.f * acc[l]);
    } else if (t < 196) {
#pragma unroll
        for (int l = 0; l < 9; ++l)
            atomicAdd(&Y[((size_t)b * 9 + l) * Q_ + t], acc[l]);
    }
}

// ====== K_C: maps = softmax_l( logits_accum + 2*upsample(Y) - asq )  (fused)
__global__ __launch_bounds__(256) void kC(const float* __restrict__ logits,
                                          const float* __restrict__ Y,
                                          const float* __restrict__ asq,
                                          float* __restrict__ out_maps) {
    int g = blockIdx.x * 256 + threadIdx.x;   // 98 blocks, exact fit
    int b = g / P_, p = g % P_;
    int yy = p / 28, xx = p % 28;
    float sy = 0.5f * yy - 0.25f, sx = 0.5f * xx - 0.25f;
    float fyf = floorf(sy), fxf = floorf(sx);
    float fy = sy - fyf, fx = sx - fxf;
    int ya = max(0, (int)fyf), yb = min(13, (int)fyf + 1);
    int xa = max(0, (int)fxf), xb = min(13, (int)fxf + 1);
    float w00 = (1.f - fy) * (1.f - fx), w01 = (1.f - fy) * fx;
    float w10 = fy * (1.f - fx),         w11 = fy * fx;
    float v[9];
#pragma unroll
    for (int l = 0; l < 9; ++l) {
        const float* Yl = Y + ((size_t)b * 9 + l) * Q_;
        float ab4 = w00 * Yl[ya * 14 + xa] + w01 * Yl[ya * 14 + xb]
                  + w10 * Yl[yb * 14 + xa] + w11 * Yl[yb * 14 + xb];
        v[l] = logits[(size_t)l * NG_ + g] + 2.f * ab4 - asq[l];
    }
    float m = v[0];
#pragma unroll
    for (int l = 1; l < 9; ++l) m = fmaxf(m, v[l]);
    float sum = 0.f;
#pragma unroll
    for (int l = 0; l < 9; ++l) { v[l] = expf(v[l] - m); sum += v[l]; }
    float inv = 1.f / sum;
#pragma unroll
    for (int l = 0; l < 9; ++l)
        out_maps[(size_t)b * (L_ * P_) + l * P_ + p] = v[l] * inv;
}

// ============== K_D: adjoint bilinear downsample of maps -> Mp[b,l,q]
__device__ __forceinline__ int adj_taps(int q, int* ys, float* wy) {
    if (q == 0)  { ys[0] = 0;  wy[0] = 1.00f; ys[1] = 1;  wy[1] = 0.75f;
                   ys[2] = 2;  wy[2] = 0.25f; return 3; }
    if (q == 13) { ys[0] = 25; wy[0] = 0.25f; ys[1] = 26; wy[1] = 0.75f;
                   ys[2] = 27; wy[2] = 1.00f; return 3; }
    ys[0] = 2 * q - 1; wy[0] = 0.25f;
    ys[1] = 2 * q;     wy[1] = 0.75f;
    ys[2] = 2 * q + 1; wy[2] = 0.75f;
    ys[3] = 2 * q + 2; wy[3] = 0.25f;
    return 4;
}

__global__ __launch_bounds__(256) void kD(const float* __restrict__ maps,
                                          float* __restrict__ Mp) {
    int tid = blockIdx.x * 256 + threadIdx.x;
    if (tid >= 32 * 9 * Q_) return;
    int b = tid / (9 * Q_);
    int r = tid % (9 * Q_);
    int l = r / Q_, q = r % Q_;
    int qy = q / 14, qx = q % 14;
    int ys[4], xs[4]; float wy[4], wx[4];
    int ny = adj_taps(qy, ys, wy);
    int nx = adj_taps(qx, xs, wx);
    const float* mrow = maps + (size_t)b * (L_ * P_) + l * P_;
    float s = 0.f;
    for (int i = 0; i < ny; ++i) {
        float rs = 0.f;
        for (int j = 0; j < nx; ++j)
            rs = fmaf(wx[j], mrow[ys[i] * 28 + xs[j]], rs);
        s = fmaf(wy[i], rs, s);
    }
    Mp[(size_t)b * (9 * Q_) + r] = s;
}

// ===================== K_E (v8): direct-global MFMA, no LDS, no barriers
// Key insight: the MFMA A-fragment for lane (row16,quad) is 8 CONTIGUOUS
// floats of one channel row -> load it straight from global. Per wave-instr
// the 64 lanes cover 16 rows x one full 128B cacheline: perfectly coalesced.
// 13 independent A float4 loads + B loads per chunk in straight-line code
// give guaranteed deep MLP per wave; zero __syncthreads (no gang-stall).
// blocks [0,1024): l4, b=bid>>5, grp 0..31, K=196 (1 chunk) vs Mp.
// blocks [1024,1536): l3, b=idx>>4, grp 0..15, K=784 (4 chunks, acc carried).
// Epilogue (verified r7): af FINAL (/784) + mf via 16-lane shfl tree.
__global__ __launch_bounds__(256, 3) void kE(
        const float* __restrict__ l3, const float* __restrict__ l4,
        const float* __restrict__ maps, const float* __restrict__ Mp,
        const float* __restrict__ mod,
        float* __restrict__ out_af, float* __restrict__ mf) {
    int bid = blockIdx.x;
    int t = threadIdx.x;
    int wave = t >> 6, lane = t & 63;
    int row16 = lane & 15, quad = lane >> 4;

    bool isl4 = (bid < 1024);
    int b, c0, nchunk, cglob0, pitch;
    const float* xsrc; const float* bsrc;
    if (isl4) {
        b = bid >> 5; c0 = (bid & 31) * 64; nchunk = 1;
        xsrc = l4 + ((size_t)b * C4_ + c0) * Q_;
        bsrc = Mp + (size_t)b * (9 * Q_);
        pitch = Q_;
        cglob0 = c0;
    } else {
        int idx = bid - 1024;
        b = idx >> 4; c0 = (idx & 15) * 64; nchunk = 4;
        xsrc = l3 + ((size_t)b * C3_ + c0) * P_;
        bsrc = maps + (size_t)b * (L_ * P_);
        pitch = P_;
        cglob0 = C4_ + c0;
    }
    // this lane's channel row (MFMA A row = row16 within the wave's 16 rows)
    const float* arow = xsrc + (size_t)(wave * 16 + row16) * pitch;
    const float* brow = bsrc + (size_t)row16 * pitch;   // valid if row16 < 9

    f32x4 acc = {0.f, 0.f, 0.f, 0.f};
    for (int h = 0; h < nchunk; ++h) {
        int koff = h * 196;
        // ---- A: 12 full float4 + s=6 tail (quad 0 only; k=192..195) ----
        float4 a[13];
#pragma unroll
        for (int s = 0; s < 6; ++s) {
            int k0 = koff + s * 32 + quad * 8;
            a[2 * s]     = *(const float4*)(arow + k0);
            a[2 * s + 1] = *(const float4*)(arow + k0 + 4);
        }
        a[12] = make_float4(0.f, 0.f, 0.f, 0.f);
        if (quad == 0) a[12] = *(const float4*)(arow + koff + 192);

        // ---- B: maps/Mp (L2-hot), convert to bf16 frags ----
        bf16x8 bfr[7];
#pragma unroll
        for (int s = 0; s < 7; ++s) {
            int k0 = s * 32 + quad * 8;
            bf16x8 bv = {0, 0, 0, 0, 0, 0, 0, 0};
            if (row16 < 9) {
                const float* bp = brow + koff + k0;
                if (s < 6) {
                    float4 b0 = *(const float4*)(bp);
                    float4 b1 = *(const float4*)(bp + 4);
                    bv[0] = f2bf(b0.x); bv[1] = f2bf(b0.y);
                    bv[2] = f2bf(b0.z); bv[3] = f2bf(b0.w);
                    bv[4] = f2bf(b1.x); bv[5] = f2bf(b1.y);
                    bv[6] = f2bf(b1.z); bv[7] = f2bf(b1.w);
                } else if (quad == 0) {        // k0=192: cols 192..195 only
                    float4 b0 = *(const float4*)(bp);
                    bv[0] = f2bf(b0.x); bv[1] = f2bf(b0.y);
                    bv[2] = f2bf(b0.z); bv[3] = f2bf(b0.w);
                }
            }
            bfr[s] = bv;
        }

        // ---- convert A + 7 MFMAs ----
#pragma unroll
        for (int s = 0; s < 7; ++s) {
            bf16x8 av = {0, 0, 0, 0, 0, 0, 0, 0};
            if (s < 6) {
                float4 a0 = a[2 * s], a1 = a[2 * s + 1];
                av[0] = f2bf(a0.x); av[1] = f2bf(a0.y);
                av[2] = f2bf(a0.z); av[3] = f2bf(a0.w);
                av[4] = f2bf(a1.x); av[5] = f2bf(a1.y);
                av[6] = f2bf(a1.z); av[7] = f2bf(a1.w);
            } else if (quad == 0) {
                float4 a0 = a[12];
                av[0] = f2bf(a0.x); av[1] = f2bf(a0.y);
                av[2] = f2bf(a0.z); av[3] = f2bf(a0.w);
            }
            acc = __builtin_amdgcn_mfma_f32_16x16x32_bf16(av, bfr[s], acc,
                                                          0, 0, 0);
        }
    }

    // ---- epilogue: af (final) + mf (verified r4/r7 scheme) ----
    int l = row16;
    int cg = cglob0 + wave * 16 + quad * 4;
    float afv[4];
#pragma unroll
    for (int r = 0; r < 4; ++r) afv[r] = acc[r] * (1.f / 784.f);
    if (l < 9) {
        size_t base = ((size_t)b * C_ + cg) * 9 + l;
#pragma unroll
        for (int r = 0; r < 4; ++r) out_af[base + (size_t)r * 9] = afv[r];
    }
    float term[4];
#pragma unroll
    for (int r = 0; r < 4; ++r)
        term[r] = (l < 8) ? afv[r] * mod[(size_t)(cg + r) * 9 + l] : 0.f;
#pragma unroll
    for (int s = 1; s < 16; s <<= 1)
#pragma unroll
        for (int r = 0; r < 4; ++r) term[r] += __shfl_xor(term[r], s);
    if (row16 == 0) {
#pragma unroll
        for (int r = 0; r < 4; ++r)
            mf[(size_t)b * C_ + cg + r] = term[r] * 0.125f;
    }
}

// -------------------------------------------------- K_F: attr = mf @ attr_w.T
__global__ __launch_bounds__(256) void kF(
        const float* __restrict__ mf, const float* __restrict__ attr_w,
        const float* __restrict__ attr_b, float* __restrict__ out_attr) {
    int idx = blockIdx.x * 4 + (threadIdx.x >> 6);   // idx = b*312 + a
    int lane = threadIdx.x & 63;
    int b = idx / A_, a = idx % A_;
    const float4* wr = (const float4*)(attr_w + (size_t)a * C_);
    const float4* mr = (const float4*)(mf + (size_t)b * C_);
    float acc = 0.f;
    for (int j = lane; j < C_ / 4; j += 64) {
        float4 w = wr[j], m = mr[j];
        acc += w.x * m.x + w.y * m.y + w.z * m.z + w.w * m.w;
    }
    acc += __shfl_xor(acc, 1);  acc += __shfl_xor(acc, 2);
    acc += __shfl_xor(acc, 4);  acc += __shfl_xor(acc, 8);
    acc += __shfl_xor(acc, 16); acc += __shfl_xor(acc, 32);
    if (lane == 0) out_attr[idx] = acc + attr_b[a];
}

// ---------------------------------------------- K_G: class = attr @ class_w.T
__global__ __launch_bounds__(256) void kG(
        const float* __restrict__ attr, const float* __restrict__ class_w,
        float* __restrict__ out_class) {
    int idx = blockIdx.x * 4 + (threadIdx.x >> 6);   // idx = b*200 + n
    int lane = threadIdx.x & 63;
    int b = idx / NC_, n = idx % NC_;
    float acc = 0.f;
    for (int a = lane; a < A_; a += 64)
        acc += attr[b * A_ + a] * class_w[n * A_ + a];
    acc += __shfl_xor(acc, 1);  acc += __shfl_xor(acc, 2);
    acc += __shfl_xor(acc, 4);  acc += __shfl_xor(acc, 8);
    acc += __shfl_xor(acc, 16); acc += __shfl_xor(acc, 32);
    if (lane == 0) out_class[idx] = acc;
}

extern "C" void kernel_launch(void* const* d_in, const int* in_sizes, int n_in,
                              void* d_out, int out_size, void* d_ws, size_t ws_size,
                              hipStream_t stream) {
    (void)in_sizes; (void)n_in; (void)out_size; (void)ws_size;
    const float* l3         = (const float*)d_in[0];
    const float* l4         = (const float*)d_in[1];
    const float* conv_w     = (const float*)d_in[2];
    const float* modulation = (const float*)d_in[3];
    const float* attr_w     = (const float*)d_in[4];
    const float* attr_b     = (const float*)d_in[5];
    const float* class_w    = (const float*)d_in[6];
    float* out = (float*)d_out;
    float* ws  = (float*)d_ws;
    float* asq    = ws + ASQ_OFF;
    float* mf     = ws + MF_OFF;
    float* logits = ws + LOGITS_OFF;
    float* Y      = ws + Y_OFF;
    float* Mp     = ws + MP_OFF;

    zK<<<1104, 256, 0, stream>>>(conv_w, Y, logits, asq);
    kA<<<2592, 256, 0, stream>>>(l3, l4, conv_w, logits, Y);
    kC<<<98, 256, 0, stream>>>(logits, Y, asq, out + MAPS_OFF);
    kD<<<221, 256, 0, stream>>>(out + MAPS_OFF, Mp);
    kE<<<1536, 256, 0, stream>>>(l3, l4, out + MAPS_OFF, Mp, modulation,
                                 out + AF_OFF, mf);
    kF<<<(B_ * A_) / 4, 256, 0, stream>>>(mf, attr_w, attr_b, out + ATTR_OFF);
    kG<<<(B_ * NC_) / 4, 256, 0, stream>>>(out + ATTR_OFF, class_w,
                                           out + CLASS_OFF);
}

// Round 9
// 268.065 us; speedup vs baseline: 1.3887x; 1.1333x over previous
//
#include <hip/hip_runtime.h>
#include <math.h>

// Problem constants
#define B_    32
#define C3_   1024
#define C4_   2048
#define C_    3072
#define P_    784      // 28*28
#define Q_    196      // 14*14
#define L_    9
#define NG_   25088    // B_*P_
#define A_    312
#define NC_   200

// d_out layout (floats): attr(32x312), class(32x200), maps(32x9x784), af(32x3072x9)
#define ATTR_OFF  0
#define CLASS_OFF 9984
#define MAPS_OFF  16384
#define AF_OFF    242176

// workspace layout (floats)
#define ASQ_OFF   0
#define MF_OFF    16
#define LOGITS_OFF 98320                          // 9 x NG_ = 225792
#define Y_OFF     (LOGITS_OFF + 9 * NG_)          // 324112 ; 32 x 9 x 196
#define MP_OFF    (Y_OFF + 32 * 9 * Q_)           // 380560 ; 32 x 9 x 196
// NOTE: zK zeroes [LOGITS_OFF, Y_OFF+32*9*Q_) as ONE contiguous float4 range
// (282240 floats = 70560 float4) -- logits and Y must stay adjacent.

typedef __attribute__((ext_vector_type(8))) short bf16x8;
typedef __attribute__((ext_vector_type(4))) float f32x4;

__device__ __forceinline__ short f2bf(float f) {
    union { float f; unsigned u; } v; v.f = f;
    unsigned r = v.u + 0x7FFFu + ((v.u >> 16) & 1u);   // RNE
    return (short)(r >> 16);
}

// async global->LDS, 16B per lane, LDS dest = uniform base + lane*16
#define GLDS16(gp, lp) __builtin_amdgcn_global_load_lds(                    \
        (const __attribute__((address_space(1))) unsigned int*)(gp),        \
        (__attribute__((address_space(3))) unsigned int*)(lp), 16, 0, 0)

// ============ zK (v9): blocks 0..8 compute asq[l] in parallel (float4);
// blocks 9..284 zero logits+Y as float4 (70560 vecs). Old single-block asq
// (~72 syncthreads + strided scalar loads) was ~20us and gates kA.
__global__ __launch_bounds__(256) void zK(const float* __restrict__ conv_w,
                                          float* __restrict__ zbase,
                                          float* __restrict__ asq) {
    int bx = blockIdx.x, t = threadIdx.x;
    if (bx < 9) {
        __shared__ float red[256];
        const float4* w = (const float4*)(conv_w + (size_t)bx * C_);
        float s = 0.f;
#pragma unroll
        for (int i = 0; i < 3; ++i) {        // 768 float4 = 3 x 256
            float4 v = w[t + i * 256];
            s += v.x + v.y + v.z + v.w;
        }
        red[t] = s; __syncthreads();
        for (int o = 128; o > 0; o >>= 1) {
            if (t < o) red[t] += red[t + o];
            __syncthreads();
        }
        if (t == 0) asq[bx] = red[0];
        return;
    }
    int i = (bx - 9) * 256 + t;
    if (i < 70560)
        ((float4*)zbase)[i] = make_float4(0.f, 0.f, 0.f, 0.f);
}

// ============================================================= K_A (round-4)
// Best measured engine (65us): chunked GLDS pipeline, 2x16KB LDS dbuf
// (5 blk/CU), 64ch = 4 chunks of 16, counted vmcnt(4), device-scope atomic
// epilogue into logits (x2) / Y.
//   blocks [0,1568): l3.  slab = bid/98, g-tile = bid%98.
//   blocks [1568,2592): l4. b = idx>>5, grp = idx&31.
__global__ __launch_bounds__(256, 5) void kA(
        const float* __restrict__ l3, const float* __restrict__ l4,
        const float* __restrict__ conv_w,
        float* __restrict__ logits, float* __restrict__ Y) {
    __shared__ float X[2][16 * 256];   // 32768 B -> 5 blocks/CU
    int bid = blockIdx.x;
    int t = threadIdx.x;
    int wave = t >> 6, lane = t & 63;

    bool isl3 = (bid < 1568);
    int slab = 0, g0 = 0, b = 0, grp = 0, cbase_w;
    const float* gbase;     // per-lane base address for channel-row 0
    size_t rowpitch;
    if (isl3) {
        slab = bid / 98;                 // block-uniform
        g0 = (bid % 98) * 256;
        int gidx = g0 + lane * 4;        // 4 floats (16B) per lane
        int bb = gidx / 784, px = gidx % 784;   // 4 | 784 -> no group split
        gbase = l3 + ((size_t)bb * C3_ + slab * 64) * P_ + px;
        rowpitch = P_;
        cbase_w = C4_ + slab * 64;
    } else {
        int idx = bid - 1568;
        b = idx >> 5; grp = idx & 31;    // block-uniform
        int q = lane * 4;
        if (q > 192) q = 192;            // lanes 49..63: dup same 16B (1 line)
        gbase = l4 + ((size_t)b * C4_ + grp * 64) * Q_ + q;
        rowpitch = Q_;
        cbase_w = grp * 64;
    }

    // prologue: chunk 0 -> buf 0 (wave w stages in-chunk rows w*4..w*4+3)
#pragma unroll
    for (int r = 0; r < 4; ++r) {
        int row = wave * 4 + r;
        GLDS16(gbase + (size_t)row * rowpitch, &X[0][row * 256]);
    }

    float acc[9];
#pragma unroll
    for (int l = 0; l < 9; ++l) acc[l] = 0.f;

#pragma unroll
    for (int j = 0; j < 4; ++j) {
        const int cur = j & 1;
        if (j < 3) {
#pragma unroll
            for (int r = 0; r < 4; ++r) {
                int row = wave * 4 + r;           // in-chunk row
                int ch = (j + 1) * 16 + row;      // global channel row
                GLDS16(gbase + (size_t)ch * rowpitch, &X[cur ^ 1][row * 256]);
            }
            // counted wait: own chunk-j loads (oldest 4) done; chunk j+1's
            // 4 loads stay in flight across the barrier.
            asm volatile("s_waitcnt vmcnt(4)" ::: "memory");
        } else {
            asm volatile("s_waitcnt vmcnt(0)" ::: "memory");
        }
        __builtin_amdgcn_s_barrier();      // all waves' chunk-j rows in LDS

        if (isl3 || t < 196) {
#pragma unroll
            for (int c = 0; c < 16; ++c) {
                float x = X[cur][c * 256 + t];
#pragma unroll
                for (int l = 0; l < 9; ++l)
                    acc[l] = fmaf(conv_w[(size_t)l * C_ + cbase_w + j * 16 + c],
                                  x, acc[l]);
            }
        }
        __builtin_amdgcn_s_barrier();      // reads done before buf reuse
    }

    if (isl3) {
#pragma unroll
        for (int l = 0; l < 9; ++l)
            atomicAdd(&logits[(size_t)l * NG_ + g0 + t], 2.f * acc[l]);
    } else if (t < 196) {
#pragma unroll
        for (int l = 0; l < 9; ++l)
            atomicAdd(&Y[((size_t)b * 9 + l) * Q_ + t], acc[l]);
    }
}

// ====== K_C: maps = softmax_l( logits_accum + 2*upsample(Y) - asq )  (fused)
__global__ __launch_bounds__(256) void kC(const float* __restrict__ logits,
                                          const float* __restrict__ Y,
                                          const float* __restrict__ asq,
                                          float* __restrict__ out_maps) {
    int g = blockIdx.x * 256 + threadIdx.x;   // 98 blocks, exact fit
    int b = g / P_, p = g % P_;
    int yy = p / 28, xx = p % 28;
    float sy = 0.5f * yy - 0.25f, sx = 0.5f * xx - 0.25f;
    float fyf = floorf(sy), fxf = floorf(sx);
    float fy = sy - fyf, fx = sx - fxf;
    int ya = max(0, (int)fyf), yb = min(13, (int)fyf + 1);
    int xa = max(0, (int)fxf), xb = min(13, (int)fxf + 1);
    float w00 = (1.f - fy) * (1.f - fx), w01 = (1.f - fy) * fx;
    float w10 = fy * (1.f - fx),         w11 = fy * fx;
    float v[9];
#pragma unroll
    for (int l = 0; l < 9; ++l) {
        const float* Yl = Y + ((size_t)b * 9 + l) * Q_;
        float ab4 = w00 * Yl[ya * 14 + xa] + w01 * Yl[ya * 14 + xb]
                  + w10 * Yl[yb * 14 + xa] + w11 * Yl[yb * 14 + xb];
        v[l] = logits[(size_t)l * NG_ + g] + 2.f * ab4 - asq[l];
    }
    float m = v[0];
#pragma unroll
    for (int l = 1; l < 9; ++l) m = fmaxf(m, v[l]);
    float sum = 0.f;
#pragma unroll
    for (int l = 0; l < 9; ++l) { v[l] = expf(v[l] - m); sum += v[l]; }
    float inv = 1.f / sum;
#pragma unroll
    for (int l = 0; l < 9; ++l)
        out_maps[(size_t)b * (L_ * P_) + l * P_ + p] = v[l] * inv;
}

// ============== K_D: adjoint bilinear downsample of maps -> Mp[b,l,q]
__device__ __forceinline__ int adj_taps(int q, int* ys, float* wy) {
    if (q == 0)  { ys[0] = 0;  wy[0] = 1.00f; ys[1] = 1;  wy[1] = 0.75f;
                   ys[2] = 2;  wy[2] = 0.25f; return 3; }
    if (q == 13) { ys[0] = 25; wy[0] = 0.25f; ys[1] = 26; wy[1] = 0.75f;
                   ys[2] = 27; wy[2] = 1.00f; return 3; }
    ys[0] = 2 * q - 1; wy[0] = 0.25f;
    ys[1] = 2 * q;     wy[1] = 0.75f;
    ys[2] = 2 * q + 1; wy[2] = 0.75f;
    ys[3] = 2 * q + 2; wy[3] = 0.25f;
    return 4;
}

__global__ __launch_bounds__(256) void kD(const float* __restrict__ maps,
                                          float* __restrict__ Mp) {
    int tid = blockIdx.x * 256 + threadIdx.x;
    if (tid >= 32 * 9 * Q_) return;
    int b = tid / (9 * Q_);
    int r = tid % (9 * Q_);
    int l = r / Q_, q = r % Q_;
    int qy = q / 14, qx = q % 14;
    int ys[4], xs[4]; float wy[4], wx[4];
    int ny = adj_taps(qy, ys, wy);
    int nx = adj_taps(qx, xs, wx);
    const float* mrow = maps + (size_t)b * (L_ * P_) + l * P_;
    float s = 0.f;
    for (int i = 0; i < ny; ++i) {
        float rs = 0.f;
        for (int j = 0; j < nx; ++j)
            rs = fmaf(wx[j], mrow[ys[i] * 28 + xs[j]], rs);
        s = fmaf(wy[i], rs, s);
    }
    Mp[(size_t)b * (9 * Q_) + r] = s;
}

// ===================== K_E (v8, kept): direct-global MFMA, no LDS/barriers
// blocks [0,1024): l4, b=bid>>5, grp 0..31, K=196 (1 chunk) vs Mp.
// blocks [1024,1536): l3, b=idx>>4, grp 0..15, K=784 (4 chunks, acc carried).
// Epilogue: af FINAL (/784) + mf via 16-lane shfl tree.
__global__ __launch_bounds__(256, 3) void kE(
        const float* __restrict__ l3, const float* __restrict__ l4,
        const float* __restrict__ maps, const float* __restrict__ Mp,
        const float* __restrict__ mod,
        float* __restrict__ out_af, float* __restrict__ mf) {
    int bid = blockIdx.x;
    int t = threadIdx.x;
    int wave = t >> 6, lane = t & 63;
    int row16 = lane & 15, quad = lane >> 4;

    bool isl4 = (bid < 1024);
    int b, c0, nchunk, cglob0, pitch;
    const float* xsrc; const float* bsrc;
    if (isl4) {
        b = bid >> 5; c0 = (bid & 31) * 64; nchunk = 1;
        xsrc = l4 + ((size_t)b * C4_ + c0) * Q_;
        bsrc = Mp + (size_t)b * (9 * Q_);
        pitch = Q_;
        cglob0 = c0;
    } else {
        int idx = bid - 1024;
        b = idx >> 4; c0 = (idx & 15) * 64; nchunk = 4;
        xsrc = l3 + ((size_t)b * C3_ + c0) * P_;
        bsrc = maps + (size_t)b * (L_ * P_);
        pitch = P_;
        cglob0 = C4_ + c0;
    }
    const float* arow = xsrc + (size_t)(wave * 16 + row16) * pitch;
    const float* brow = bsrc + (size_t)row16 * pitch;   // valid if row16 < 9

    f32x4 acc = {0.f, 0.f, 0.f, 0.f};
    for (int h = 0; h < nchunk; ++h) {
        int koff = h * 196;
        float4 a[13];
#pragma unroll
        for (int s = 0; s < 6; ++s) {
            int k0 = koff + s * 32 + quad * 8;
            a[2 * s]     = *(const float4*)(arow + k0);
            a[2 * s + 1] = *(const float4*)(arow + k0 + 4);
        }
        a[12] = make_float4(0.f, 0.f, 0.f, 0.f);
        if (quad == 0) a[12] = *(const float4*)(arow + koff + 192);

        bf16x8 bfr[7];
#pragma unroll
        for (int s = 0; s < 7; ++s) {
            int k0 = s * 32 + quad * 8;
            bf16x8 bv = {0, 0, 0, 0, 0, 0, 0, 0};
            if (row16 < 9) {
                const float* bp = brow + koff + k0;
                if (s < 6) {
                    float4 b0 = *(const float4*)(bp);
                    float4 b1 = *(const float4*)(bp + 4);
                    bv[0] = f2bf(b0.x); bv[1] = f2bf(b0.y);
                    bv[2] = f2bf(b0.z); bv[3] = f2bf(b0.w);
                    bv[4] = f2bf(b1.x); bv[5] = f2bf(b1.y);
                    bv[6] = f2bf(b1.z); bv[7] = f2bf(b1.w);
                } else if (quad == 0) {        // k0=192: cols 192..195 only
                    float4 b0 = *(const float4*)(bp);
                    bv[0] = f2bf(b0.x); bv[1] = f2bf(b0.y);
                    bv[2] = f2bf(b0.z); bv[3] = f2bf(b0.w);
                }
            }
            bfr[s] = bv;
        }

#pragma unroll
        for (int s = 0; s < 7; ++s) {
            bf16x8 av = {0, 0, 0, 0, 0, 0, 0, 0};
            if (s < 6) {
                float4 a0 = a[2 * s], a1 = a[2 * s + 1];
                av[0] = f2bf(a0.x); av[1] = f2bf(a0.y);
                av[2] = f2bf(a0.z); av[3] = f2bf(a0.w);
                av[4] = f2bf(a1.x); av[5] = f2bf(a1.y);
                av[6] = f2bf(a1.z); av[7] = f2bf(a1.w);
            } else if (quad == 0) {
                float4 a0 = a[12];
                av[0] = f2bf(a0.x); av[1] = f2bf(a0.y);
                av[2] = f2bf(a0.z); av[3] = f2bf(a0.w);
            }
            acc = __builtin_amdgcn_mfma_f32_16x16x32_bf16(av, bfr[s], acc,
                                                          0, 0, 0);
        }
    }

    // ---- epilogue: af (final) + mf (verified r4/r7 scheme) ----
    int l = row16;
    int cg = cglob0 + wave * 16 + quad * 4;
    float afv[4];
#pragma unroll
    for (int r = 0; r < 4; ++r) afv[r] = acc[r] * (1.f / 784.f);
    if (l < 9) {
        size_t base = ((size_t)b * C_ + cg) * 9 + l;
#pragma unroll
        for (int r = 0; r < 4; ++r) out_af[base + (size_t)r * 9] = afv[r];
    }
    float term[4];
#pragma unroll
    for (int r = 0; r < 4; ++r)
        term[r] = (l < 8) ? afv[r] * mod[(size_t)(cg + r) * 9 + l] : 0.f;
#pragma unroll
    for (int s = 1; s < 16; s <<= 1)
#pragma unroll
        for (int r = 0; r < 4; ++r) term[r] += __shfl_xor(term[r], s);
    if (row16 == 0) {
#pragma unroll
        for (int r = 0; r < 4; ++r)
            mf[(size_t)b * C_ + cg + r] = term[r] * 0.125f;
    }
}

// ============== K_F (v9): attr = mf @ attr_w.T, attr_w staged ONCE per block
// Old form read attr_w once PER OUTPUT -> 122 MB L2/L3 traffic (~45us,
// hidden just under kA in top-5). New: 312 blocks (one per a); stage
// attr_w[a,:] in LDS (12 KB float4); 8 lanes per batch b dot 3072 against
// L2-hot mf; shfl_xor(1,2,4) reduce. attr_w traffic: 3.8 MB total (32x less).
__global__ __launch_bounds__(256) void kF(
        const float* __restrict__ mf, const float* __restrict__ attr_w,
        const float* __restrict__ attr_b, float* __restrict__ out_attr) {
    __shared__ float sw[C_];               // 12288 B
    int a = blockIdx.x, t = threadIdx.x;
    const float4* wr = (const float4*)(attr_w + (size_t)a * C_);
#pragma unroll
    for (int i = 0; i < 3; ++i)            // 768 float4 = 3 x 256
        ((float4*)sw)[t + i * 256] = wr[t + i * 256];
    __syncthreads();

    int b = t >> 3, j = t & 7;             // 8 lanes per batch
    const float* mrow = mf + (size_t)b * C_;
    float acc = 0.f;
#pragma unroll 8
    for (int m = 0; m < 96; ++m) {         // k = j*4 + m*32 covers K once
        int k = j * 4 + m * 32;
        float4 mv = *(const float4*)(mrow + k);
        float4 wv = *(const float4*)(sw + k);   // broadcast across b-groups
        acc += mv.x * wv.x + mv.y * wv.y + mv.z * wv.z + mv.w * wv.w;
    }
    acc += __shfl_xor(acc, 1);
    acc += __shfl_xor(acc, 2);
    acc += __shfl_xor(acc, 4);
    if (j == 0) out_attr[(size_t)b * A_ + a] = acc + attr_b[a];
}

// ---------------------------------------------- K_G: class = attr @ class_w.T
__global__ __launch_bounds__(256) void kG(
        const float* __restrict__ attr, const float* __restrict__ class_w,
        float* __restrict__ out_class) {
    int idx = blockIdx.x * 4 + (threadIdx.x >> 6);   // idx = b*200 + n
    int lane = threadIdx.x & 63;
    int b = idx / NC_, n = idx % NC_;
    float acc = 0.f;
    for (int a = lane; a < A_; a += 64)
        acc += attr[b * A_ + a] * class_w[n * A_ + a];
    acc += __shfl_xor(acc, 1);  acc += __shfl_xor(acc, 2);
    acc += __shfl_xor(acc, 4);  acc += __shfl_xor(acc, 8);
    acc += __shfl_xor(acc, 16); acc += __shfl_xor(acc, 32);
    if (lane == 0) out_class[idx] = acc;
}

extern "C" void kernel_launch(void* const* d_in, const int* in_sizes, int n_in,
                              void* d_out, int out_size, void* d_ws, size_t ws_size,
                              hipStream_t stream) {
    (void)in_sizes; (void)n_in; (void)out_size; (void)ws_size;
    const float* l3         = (const float*)d_in[0];
    const float* l4         = (const float*)d_in[1];
    const float* conv_w     = (const float*)d_in[2];
    const float* modulation = (const float*)d_in[3];
    const float* attr_w     = (const float*)d_in[4];
    const float* attr_b     = (const float*)d_in[5];
    const float* class_w    = (const float*)d_in[6];
    float* out = (float*)d_out;
    float* ws  = (float*)d_ws;
    float* asq    = ws + ASQ_OFF;
    float* mf     = ws + MF_OFF;
    float* logits = ws + LOGITS_OFF;
    float* Y      = ws + Y_OFF;
    float* Mp     = ws + MP_OFF;

    zK<<<285, 256, 0, stream>>>(conv_w, logits /* zero base: logits+Y */, asq);
    kA<<<2592, 256, 0, stream>>>(l3, l4, conv_w, logits, Y);
    kC<<<98, 256, 0, stream>>>(logits, Y, asq, out + MAPS_OFF);
    kD<<<221, 256, 0, stream>>>(out + MAPS_OFF, Mp);
    kE<<<1536, 256, 0, stream>>>(l3, l4, out + MAPS_OFF, Mp, modulation,
                                 out + AF_OFF, mf);
    kF<<<A_, 256, 0, stream>>>(mf, attr_w, attr_b, out + ATTR_OFF);
    kG<<<(B_ * NC_) / 4, 256, 0, stream>>>(out + ATTR_OFF, class_w,
                                           out + CLASS_OFF);
}